// Round 2
// baseline (684.003 us; speedup 1.0000x reference)
//
#include <hip/hip_runtime.h>
#include <hip/hip_bf16.h>
#include <math.h>

// Problem constants (B=2048, D=512, C=100000)
constexpr int Bq = 2048;
constexpr int Dq = 512;
constexpr int Cq = 100000;
constexpr int NPAD = 100096;     // 782 * 128 (N padded to tile multiple)

constexpr float SCALE = 64.0f;
constexpr float COS_M = 0.8775825618903728f;   // cos(0.5)
constexpr float SIN_M = 0.479425538604203f;    // sin(0.5)
constexpr float THR   = -0.8775825618903728f;  // cos(pi - 0.5)
constexpr float MM    = 0.2397127693021015f;   // sin(pi - 0.5) * 0.5

typedef __attribute__((ext_vector_type(8))) __bf16 bf16x8;
typedef __attribute__((ext_vector_type(4))) float f32x4;

typedef const __attribute__((address_space(1))) unsigned int guint;
typedef __attribute__((address_space(3))) unsigned int suint;

__device__ __forceinline__ void gload_lds16(const unsigned short* g, unsigned short* lds)
{
    // width=16B direct global->LDS; LDS dest is wave-uniform base + lane*16
    __builtin_amdgcn_global_load_lds((guint*)g, (suint*)lds, 16, 0, 0);
}

// ---------------------------------------------------------------------------
// Row L2-normalize fp32 [nrows][512] -> bf16 [gridDim.x][512] (pad rows -> 0)
// ---------------------------------------------------------------------------
__global__ __launch_bounds__(256) void normalize_rows_kernel(
    const float* __restrict__ in, unsigned short* __restrict__ out, int nrows)
{
    const int row = blockIdx.x;
    const int t = threadIdx.x;
    unsigned int* out32 = (unsigned int*)out;
    if (row >= nrows) {
        out32[(size_t)row * (Dq / 2) + t] = 0u;   // zero pad rows
        return;
    }
    float2 v = reinterpret_cast<const float2*>(in + (size_t)row * Dq)[t];
    float ss = v.x * v.x + v.y * v.y;
    #pragma unroll
    for (int off = 32; off > 0; off >>= 1) ss += __shfl_down(ss, off);
    __shared__ float wsum[4];
    const int wave = t >> 6, lane = t & 63;
    if (lane == 0) wsum[wave] = ss;
    __syncthreads();
    const float total = wsum[0] + wsum[1] + wsum[2] + wsum[3];
    const float invn = 1.0f / fmaxf(sqrtf(total), 1e-12f);
    __hip_bfloat16 h0 = __float2bfloat16(v.x * invn);
    __hip_bfloat16 h1 = __float2bfloat16(v.y * invn);
    unsigned int packed = ((unsigned int)(*(unsigned short*)&h1) << 16) |
                          (unsigned int)(*(unsigned short*)&h0);
    out32[(size_t)row * (Dq / 2) + t] = packed;
}

// ---------------------------------------------------------------------------
// GEMM: A[2048][512] bf16 x Bn[NPAD][512] bf16 (B^T layout) -> out fp32
// 128x128 tile, BK=64, 4 waves (2x2), mfma_f32_16x16x32_bf16.
// LDS layout is XOR-swizzled in 16B chunks: LDS[r][c] = G[r][c ^ (r&7)].
// global_load_lds writes linearly, so the swizzle is applied by permuting the
// per-lane GLOBAL source chunk (within one 128B cacheline -> no coalescing
// loss) and XOR-ing the ds_read chunk index (rule #21: both-sides involution).
// ---------------------------------------------------------------------------
__global__ __launch_bounds__(256) void arc_gemm_kernel(
    const unsigned short* __restrict__ A,
    const unsigned short* __restrict__ Bn,
    const int* __restrict__ labels,
    float* __restrict__ out)
{
    constexpr int BM = 128, BN = 128, BK = 64;
    __shared__ unsigned short As[BM * BK];   // [128][64], 16B chunks swizzled
    __shared__ unsigned short Bs[BN * BK];

    // T1: XCD-aware bijective block swizzle (grid 12512 = 8 * 1564 exact).
    // Concurrent blocks on one XCD become consecutive bids -> 16 consecutive
    // bids share one 128KB B-strip in that XCD's L2.
    constexpr int NXCD = 8;
    const int cpx = (int)gridDim.x / NXCD;
    const int bid = ((int)blockIdx.x % NXCD) * cpx + (int)blockIdx.x / NXCD;

    const int tm = bid & 15;        // m-tile fastest within a B-strip group
    const int tn = bid >> 4;
    const int m0 = tm * BM;
    const int n0 = tn * BN;

    const int t = threadIdx.x;
    const int wave = t >> 6;
    const int lane = t & 63;
    const int wr = (wave >> 1) * 64;   // wave origin within tile
    const int wc = (wave & 1) * 64;

    // Staging: issue s covers rows [s*32, s*32+32). Thread t loads 16B:
    //   LDS row r = s*32 + (t>>3), LDS chunk c = t&7 (linear dest)
    //   global source chunk = c ^ (r&7)  (inverse swizzle)
    const int srow = t >> 3;                       // 0..31
    const int schunk = (t & 7) ^ (srow & 7);       // pre-swizzled source chunk
    const int scol = schunk * 8;                   // elements
    const unsigned short* gA = A + (size_t)(m0 + srow) * Dq + scol;
    const unsigned short* gB = Bn + (size_t)(n0 + srow) * Dq + scol;
    unsigned short* lA = As + wave * 512;   // wave-uniform LDS base
    unsigned short* lB = Bs + wave * 512;

    f32x4 acc[4][4];
    #pragma unroll
    for (int i = 0; i < 4; ++i)
        #pragma unroll
        for (int j = 0; j < 4; ++j) acc[i][j] = {0.f, 0.f, 0.f, 0.f};

    const int fr = lane & 15;   // fragment row (A) / col (B,D)
    const int kg = lane >> 4;   // k-group (0..3)
    const int s7 = fr & 7;      // row&7 of every fragment row this lane reads

    for (int kt = 0; kt < Dq / BK; ++kt) {
        #pragma unroll
        for (int s = 0; s < 4; ++s) {
            gload_lds16(gA + (size_t)(s * 32) * Dq + kt * BK, lA + s * 2048);
            gload_lds16(gB + (size_t)(s * 32) * Dq + kt * BK, lB + s * 2048);
        }
        __syncthreads();   // drains vmcnt(0) -> LDS tiles ready
        #pragma unroll
        for (int ks = 0; ks < 2; ++ks) {
            // swizzled chunk for this lane's fragment k-slice
            const int chA = (((ks * 4 + kg) ^ s7) << 3);   // element offset in row
            bf16x8 af[4], bf[4];
            #pragma unroll
            for (int mi = 0; mi < 4; ++mi)
                af[mi] = *reinterpret_cast<const bf16x8*>(
                    &As[(wr + mi * 16 + fr) * BK + chA]);
            #pragma unroll
            for (int ni = 0; ni < 4; ++ni)
                bf[ni] = *reinterpret_cast<const bf16x8*>(
                    &Bs[(wc + ni * 16 + fr) * BK + chA]);
            #pragma unroll
            for (int mi = 0; mi < 4; ++mi)
                #pragma unroll
                for (int ni = 0; ni < 4; ++ni)
                    acc[mi][ni] = __builtin_amdgcn_mfma_f32_16x16x32_bf16(
                        af[mi], bf[ni], acc[mi][ni], 0, 0, 0);
        }
        __syncthreads();   // all waves done reading before restaging
    }

    // Epilogue: D mapping col = lane&15, row = 4*(lane>>4) + reg
    const int rbase0 = m0 + wr + (lane >> 4) * 4;
    #pragma unroll
    for (int mi = 0; mi < 4; ++mi) {
        const int rbase = rbase0 + mi * 16;
        int labs[4];
        #pragma unroll
        for (int r = 0; r < 4; ++r) labs[r] = labels[rbase + r];
        #pragma unroll
        for (int ni = 0; ni < 4; ++ni) {
            const int gcol = n0 + wc + ni * 16 + fr;
            if (gcol >= Cq) continue;   // N tail guard
            f32x4 v = acc[mi][ni];
            #pragma unroll
            for (int r = 0; r < 4; ++r) {
                float c = v[r];
                float val = c;
                if (gcol == labs[r]) {   // rare: wave-uniform skip almost always
                    float sine = sqrtf(fmaxf(1.0f - c * c, 0.0f));
                    float phi = c * COS_M - sine * SIN_M;
                    val = (c > THR) ? phi : (c - MM);
                }
                out[(size_t)(rbase + r) * Cq + gcol] = val * SCALE;
            }
        }
    }
}

extern "C" void kernel_launch(void* const* d_in, const int* in_sizes, int n_in,
                              void* d_out, int out_size, void* d_ws, size_t ws_size,
                              hipStream_t stream)
{
    const float* emb    = (const float*)d_in[0];
    const int*   labels = (const int*)d_in[1];
    const float* weight = (const float*)d_in[2];
    float* out = (float*)d_out;

    unsigned short* Abf = (unsigned short*)d_ws;             // 2048*512 bf16 = 2 MB
    unsigned short* Bbf = Abf + (size_t)Bq * Dq;             // NPAD*512 bf16 = 102.5 MB

    normalize_rows_kernel<<<Bq, 256, 0, stream>>>(emb, Abf, Bq);
    normalize_rows_kernel<<<NPAD, 256, 0, stream>>>(weight, Bbf, Cq);
    arc_gemm_kernel<<<16 * (NPAD / 128), 256, 0, stream>>>(Abf, Bbf, labels, out);
}

// Round 3
// 427.472 us; speedup vs baseline: 1.6001x; 1.6001x over previous
//
#include <hip/hip_runtime.h>
#include <hip/hip_bf16.h>
#include <math.h>

// Problem constants (B=2048, D=512, C=100000)
constexpr int Bq = 2048;
constexpr int Dq = 512;
constexpr int Cq = 100000;
constexpr int NPAD = 100096;     // 391 * 256 (N padded to tile multiple)

constexpr float SCALE = 64.0f;
constexpr float COS_M = 0.8775825618903728f;   // cos(0.5)
constexpr float SIN_M = 0.479425538604203f;    // sin(0.5)
constexpr float THR   = -0.8775825618903728f;  // cos(pi - 0.5)
constexpr float MM    = 0.2397127693021015f;   // sin(pi - 0.5) * 0.5

typedef __attribute__((ext_vector_type(8))) __bf16 bf16x8;
typedef __attribute__((ext_vector_type(4))) float f32x4;

typedef const __attribute__((address_space(1))) unsigned int guint;
typedef __attribute__((address_space(3))) unsigned int suint;

__device__ __forceinline__ void gload_lds16(const unsigned short* g, unsigned short* lds)
{
    __builtin_amdgcn_global_load_lds((guint*)g, (suint*)lds, 16, 0, 0);
}

// ---------------------------------------------------------------------------
// Row L2-normalize fp32 [nrows][512] -> bf16 (pad rows -> 0)
// ---------------------------------------------------------------------------
__global__ __launch_bounds__(256) void normalize_rows_kernel(
    const float* __restrict__ in, unsigned short* __restrict__ out, int nrows)
{
    const int row = blockIdx.x;
    const int t = threadIdx.x;
    unsigned int* out32 = (unsigned int*)out;
    if (row >= nrows) {
        out32[(size_t)row * (Dq / 2) + t] = 0u;
        return;
    }
    float2 v = reinterpret_cast<const float2*>(in + (size_t)row * Dq)[t];
    float ss = v.x * v.x + v.y * v.y;
    #pragma unroll
    for (int off = 32; off > 0; off >>= 1) ss += __shfl_down(ss, off);
    __shared__ float wsum[4];
    const int wave = t >> 6, lane = t & 63;
    if (lane == 0) wsum[wave] = ss;
    __syncthreads();
    const float total = wsum[0] + wsum[1] + wsum[2] + wsum[3];
    const float invn = 1.0f / fmaxf(sqrtf(total), 1e-12f);
    __hip_bfloat16 h0 = __float2bfloat16(v.x * invn);
    __hip_bfloat16 h1 = __float2bfloat16(v.y * invn);
    unsigned int packed = ((unsigned int)(*(unsigned short*)&h1) << 16) |
                          (unsigned int)(*(unsigned short*)&h0);
    out32[(size_t)row * (Dq / 2) + t] = packed;
}

// ---------------------------------------------------------------------------
// 256x256 8-phase GEMM (T1+T2+T3+T4+T5), BK=64, 8 waves (2M x 4N),
// per-wave output 128x64, LDS 2 x (A 32KB + B 32KB) = 128KB double buffer.
// Staging rotation (per iteration kt, units are 8KB = 64 rows x 64 K):
//   phase 0: ds B(all)+A-quad0; stage A1,A3(kt+1) -> buf[(kt+1)&1]
//   phase 1: ds A-quad1;        stage B0,B1(kt+2) -> buf[kt&1]   (B dead after ph0)
//   phase 2: ds A-quad2;        stage B2,B3(kt+2)
//   phase 3: ds A-quad3;        stage A0,A2(kt+2)  (rows 0-63/128-191, disjoint
//            from quad3 reads rows 96-127/224-255); vmcnt(6); barrier
// Per-thread vmcnt ledger: gate at each K-tile end leaves exactly the 6 newest
// loads (kt+2 partial) in flight; everything needed by kt+1 has landed.
// ---------------------------------------------------------------------------
__global__ __launch_bounds__(512, 1) void arc_gemm_kernel(
    const unsigned short* __restrict__ A,
    const unsigned short* __restrict__ Bn,
    const int* __restrict__ labels,
    float* __restrict__ out)
{
    extern __shared__ unsigned short lds[];   // 131072 B = 65536 ushort

    // T1: XCD-aware bijective swizzle (3128 = 8 * 391 exact)
    const int cpx = (int)gridDim.x >> 3;
    const int bid = ((int)blockIdx.x & 7) * cpx + ((int)blockIdx.x >> 3);
    const int tm = bid & 7;          // 8 m-tiles: consecutive bids share B-strip
    const int tn = bid >> 3;
    const int m0 = tm * 256, n0 = tn * 256;

    const int t = threadIdx.x;
    const int w = t >> 6, lane = t & 63;
    const int wr = (w >> 2) * 128;   // wave M origin (2 groups)
    const int wc = (w & 3) * 64;     // wave N origin (4 groups)
    const int fr = lane & 15, kg = lane >> 4;
    const int s7 = fr & 7;
    const int c0 = (kg ^ s7) * 8;          // swizzled chunk, ks=0 (elems)
    const int c1 = ((4 + kg) ^ s7) * 8;    // ks=1

    // staging: thread t covers row trow of each 64-row unit, swizzled source col
    const int trow = t >> 3;
    const int tch = ((t & 7) ^ (trow & 7)) * 8;
    const unsigned short* gA = A  + (size_t)(m0 + trow) * Dq + tch;
    const unsigned short* gB = Bn + (size_t)(n0 + trow) * Dq + tch;
    const int dstA = trow * 64 + (t & 7) * 8;   // elem offset within unit

#define STAGE_A(buf, u, kts) gload_lds16(gA + (size_t)(u) * 64 * Dq + (size_t)(kts) * 64, \
                                         &lds[(buf) * 32768 + (u) * 4096 + dstA])
#define STAGE_B(buf, u, kts) gload_lds16(gB + (size_t)(u) * 64 * Dq + (size_t)(kts) * 64, \
                                         &lds[(buf) * 32768 + 16384 + (u) * 4096 + dstA])
#define BARRIER() do { __builtin_amdgcn_sched_barrier(0); __builtin_amdgcn_s_barrier(); } while (0)

    f32x4 acc[8][4];
    #pragma unroll
    for (int i = 0; i < 8; ++i)
        #pragma unroll
        for (int j = 0; j < 4; ++j) acc[i][j] = {0.f, 0.f, 0.f, 0.f};

    // Prologue: K0 complete (8 units) + K1 partial (B0-3, A0, A2)
    STAGE_A(0, 0, 0); STAGE_A(0, 1, 0); STAGE_A(0, 2, 0); STAGE_A(0, 3, 0);
    STAGE_B(0, 0, 0); STAGE_B(0, 1, 0); STAGE_B(0, 2, 0); STAGE_B(0, 3, 0);
    STAGE_B(1, 0, 1); STAGE_B(1, 1, 1); STAGE_B(1, 2, 1); STAGE_B(1, 3, 1);
    STAGE_A(1, 0, 1); STAGE_A(1, 2, 1);
    asm volatile("s_waitcnt vmcnt(6)" ::: "memory");   // K0 landed, K1 partial in flight
    __builtin_amdgcn_s_barrier();

    const int arow = (wr + fr) * 64;
    const int brow = 16384 + (wc + fr) * 64;

#define LDA(q) do { \
    _Pragma("unroll") for (int m2 = 0; m2 < 2; ++m2) { \
        afr[m2][0] = *reinterpret_cast<const bf16x8*>(&lds[cbo + arow + ((q) * 32 + m2 * 16) * 64 + c0]); \
        afr[m2][1] = *reinterpret_cast<const bf16x8*>(&lds[cbo + arow + ((q) * 32 + m2 * 16) * 64 + c1]); } \
} while (0)
#define LDB() do { \
    _Pragma("unroll") for (int ni = 0; ni < 4; ++ni) { \
        bfr[ni][0] = *reinterpret_cast<const bf16x8*>(&lds[cbo + brow + ni * 1024 + c0]); \
        bfr[ni][1] = *reinterpret_cast<const bf16x8*>(&lds[cbo + brow + ni * 1024 + c1]); } \
} while (0)
#define MFMA_QUAD(q) do { \
    __builtin_amdgcn_s_setprio(1); \
    _Pragma("unroll") for (int ks = 0; ks < 2; ++ks) \
    _Pragma("unroll") for (int m2 = 0; m2 < 2; ++m2) \
    _Pragma("unroll") for (int ni = 0; ni < 4; ++ni) \
        acc[2 * (q) + m2][ni] = __builtin_amdgcn_mfma_f32_16x16x32_bf16( \
            afr[m2][ks], bfr[ni][ks], acc[2 * (q) + m2][ni], 0, 0, 0); \
    __builtin_amdgcn_s_setprio(0); \
} while (0)

    #pragma unroll
    for (int kt = 0; kt < 8; ++kt) {
        const int cb = kt & 1, nb = cb ^ 1;
        const int cbo = cb * 32768;
        bf16x8 bfr[4][2];
        // ---- phase 0: 12 ds_reads (B all + A quad0); stage A1,A3(kt+1)
        {
            bf16x8 afr[2][2];
            LDB(); LDA(0);
            if (kt < 7) { STAGE_A(nb, 1, kt + 1); STAGE_A(nb, 3, kt + 1); }
            BARRIER();
            MFMA_QUAD(0);
            BARRIER();
            // ---- phase 1: A quad1; stage B0,B1(kt+2)
            LDA(1);
            if (kt < 6) { STAGE_B(cb, 0, kt + 2); STAGE_B(cb, 1, kt + 2); }
            BARRIER();
            MFMA_QUAD(1);
            BARRIER();
            // ---- phase 2: A quad2; stage B2,B3(kt+2)
            LDA(2);
            if (kt < 6) { STAGE_B(cb, 2, kt + 2); STAGE_B(cb, 3, kt + 2); }
            BARRIER();
            MFMA_QUAD(2);
            BARRIER();
            // ---- phase 3: A quad3; stage A0,A2(kt+2); counted vmcnt gate
            LDA(3);
            if (kt < 6) { STAGE_A(cb, 0, kt + 2); STAGE_A(cb, 2, kt + 2); }
            BARRIER();
            MFMA_QUAD(3);
            if (kt < 6) asm volatile("s_waitcnt vmcnt(6)" ::: "memory");
            else        asm volatile("s_waitcnt vmcnt(0)" ::: "memory");
            BARRIER();
        }
    }

    // Epilogue: D mapping col = lane&15, row = 4*(lane>>4) + reg
    const int r0 = kg * 4;
    #pragma unroll
    for (int mi = 0; mi < 8; ++mi) {
        const int grow0 = m0 + wr + mi * 16 + r0;
        int labs[4];
        #pragma unroll
        for (int r = 0; r < 4; ++r) labs[r] = labels[grow0 + r];
        #pragma unroll
        for (int ni = 0; ni < 4; ++ni) {
            const int gcol = n0 + wc + ni * 16 + fr;
            if (gcol >= Cq) continue;
            f32x4 v = acc[mi][ni];
            #pragma unroll
            for (int r = 0; r < 4; ++r) {
                float c = v[r];
                float val = c;
                if (gcol == labs[r]) {
                    float sine = sqrtf(fmaxf(1.0f - c * c, 0.0f));
                    float phi = c * COS_M - sine * SIN_M;
                    val = (c > THR) ? phi : (c - MM);
                }
                out[(size_t)(grow0 + r) * Cq + gcol] = val * SCALE;
            }
        }
    }
#undef STAGE_A
#undef STAGE_B
#undef BARRIER
#undef LDA
#undef LDB
#undef MFMA_QUAD
}

extern "C" void kernel_launch(void* const* d_in, const int* in_sizes, int n_in,
                              void* d_out, int out_size, void* d_ws, size_t ws_size,
                              hipStream_t stream)
{
    const float* emb    = (const float*)d_in[0];
    const int*   labels = (const int*)d_in[1];
    const float* weight = (const float*)d_in[2];
    float* out = (float*)d_out;

    unsigned short* Abf = (unsigned short*)d_ws;             // 2 MB
    unsigned short* Bbf = Abf + (size_t)Bq * Dq;             // 102.5 MB

    normalize_rows_kernel<<<Bq, 256, 0, stream>>>(emb, Abf, Bq);
    normalize_rows_kernel<<<NPAD, 256, 0, stream>>>(weight, Bbf, Cq);
    arc_gemm_kernel<<<8 * (NPAD / 256), 512, 131072, stream>>>(Abf, Bbf, labels, out);
}

// Round 4
// 423.062 us; speedup vs baseline: 1.6168x; 1.0104x over previous
//
#include <hip/hip_runtime.h>
#include <hip/hip_bf16.h>
#include <math.h>

// Problem constants (B=2048, D=512, C=100000)
constexpr int Bq = 2048;
constexpr int Dq = 512;
constexpr int Cq = 100000;
constexpr int NPAD = 100096;     // 391 * 256 (N padded to tile multiple)

constexpr float SCALE = 64.0f;
constexpr float COS_M = 0.8775825618903728f;   // cos(0.5)
constexpr float SIN_M = 0.479425538604203f;    // sin(0.5)
constexpr float THR   = -0.8775825618903728f;  // cos(pi - 0.5)
constexpr float MM    = 0.2397127693021015f;   // sin(pi - 0.5) * 0.5

typedef __attribute__((ext_vector_type(8))) __bf16 bf16x8;
typedef __attribute__((ext_vector_type(4))) float f32x4;

typedef const __attribute__((address_space(1))) unsigned int guint;
typedef __attribute__((address_space(3))) unsigned int suint;

__device__ __forceinline__ void gload_lds16(const unsigned short* g, unsigned short* lds)
{
    __builtin_amdgcn_global_load_lds((guint*)g, (suint*)lds, 16, 0, 0);
}

__device__ __forceinline__ unsigned int pack_bf16x2(float lo, float hi)
{
    __hip_bfloat16 h0 = __float2bfloat16(lo);
    __hip_bfloat16 h1 = __float2bfloat16(hi);
    return ((unsigned int)(*(unsigned short*)&h1) << 16) |
           (unsigned int)(*(unsigned short*)&h0);
}

// ---------------------------------------------------------------------------
// Row L2-normalize fp32 [*][512] -> bf16, wave-per-row, float4 loads,
// pure shuffle reduce (no LDS, no barriers). 4 rows per 256-thread block.
// Rows >= nrows (padding) write zeros.
// ---------------------------------------------------------------------------
__global__ __launch_bounds__(256) void normalize_rows_kernel(
    const float* __restrict__ in, unsigned short* __restrict__ out, int nrows)
{
    const int w = threadIdx.x >> 6, lane = threadIdx.x & 63;
    const int row = blockIdx.x * 4 + w;
    float4 a = {0.f, 0.f, 0.f, 0.f}, b = a;
    if (row < nrows) {
        const float4* src = reinterpret_cast<const float4*>(in + (size_t)row * Dq);
        a = src[lane];
        b = src[lane + 64];
    }
    float ss = a.x * a.x + a.y * a.y + a.z * a.z + a.w * a.w
             + b.x * b.x + b.y * b.y + b.z * b.z + b.w * b.w;
    #pragma unroll
    for (int off = 32; off > 0; off >>= 1) ss += __shfl_down(ss, off);
    ss = __shfl(ss, 0);
    const float invn = 1.0f / fmaxf(sqrtf(ss), 1e-12f);

    uint2* out64 = reinterpret_cast<uint2*>(out + (size_t)row * Dq);
    uint2 pa, pb;
    pa.x = pack_bf16x2(a.x * invn, a.y * invn);
    pa.y = pack_bf16x2(a.z * invn, a.w * invn);
    pb.x = pack_bf16x2(b.x * invn, b.y * invn);
    pb.y = pack_bf16x2(b.z * invn, b.w * invn);
    out64[lane] = pa;          // elems [lane*4 .. +3]
    out64[lane + 64] = pb;     // elems [256 + lane*4 .. +3]
}

// ---------------------------------------------------------------------------
// 256x256 8-phase GEMM (T1+T2+T3+T4+T5), BK=64, 8 waves (2M x 4N),
// per-wave output 128x64, LDS 2 x (A 32KB + B 32KB) = 128KB double buffer.
//
// MFMA operands are SWAPPED (A-operand = class fragment, B-operand = emb
// fragment) so the D fragment holds, per lane, 4 CONSECUTIVE CLASS COLUMNS
// of one emb row:  D row (=4*kg+reg) -> class, D col (=lane&15) -> emb row.
// The epilogue then stores each acc f32x4 as one global_store_dwordx4.
//
// Staging rotation per iteration kt (units = 8KB = 64 rows x 64 K):
//   phase 0: ds B(all)+A-quad0; stage A1,A3(kt+1) -> buf[(kt+1)&1]
//   phase 1: ds A-quad1;        stage B0,B1(kt+2) -> buf[kt&1]
//   phase 2: ds A-quad2;        stage B2,B3(kt+2)
//   phase 3: ds A-quad3;        stage A0,A2(kt+2); vmcnt(6); barrier
// Ledger: the 6 newest loads at each K-tile gate are exactly the kt+2
// partials; everything needed by kt+1 has landed.
// ---------------------------------------------------------------------------
__global__ __launch_bounds__(512, 1) void arc_gemm_kernel(
    const unsigned short* __restrict__ A,
    const unsigned short* __restrict__ Bn,
    const int* __restrict__ labels,
    float* __restrict__ out)
{
    extern __shared__ unsigned short lds[];   // 131072 B

    // T1: XCD-aware bijective swizzle (3128 = 8 * 391 exact)
    const int cpx = (int)gridDim.x >> 3;
    const int bid = ((int)blockIdx.x & 7) * cpx + ((int)blockIdx.x >> 3);
    const int tm = bid & 7;          // 8 m-tiles share one B-strip per XCD
    const int tn = bid >> 3;
    const int m0 = tm * 256, n0 = tn * 256;

    const int t = threadIdx.x;
    const int w = t >> 6, lane = t & 63;
    const int wr = (w >> 2) * 128;   // wave M (emb) origin
    const int wc = (w & 3) * 64;     // wave N (class) origin
    const int fr = lane & 15, kg = lane >> 4;
    const int s7 = fr & 7;
    const int c0 = (kg ^ s7) * 8;          // swizzled chunk, ks=0 (elems)
    const int c1 = ((4 + kg) ^ s7) * 8;    // ks=1

    // staging: thread t covers row trow of each 64-row unit, swizzled src col
    const int trow = t >> 3;
    const int tch = ((t & 7) ^ (trow & 7)) * 8;
    const unsigned short* gA = A  + (size_t)(m0 + trow) * Dq + tch;
    const unsigned short* gB = Bn + (size_t)(n0 + trow) * Dq + tch;
    const int dstA = trow * 64 + (t & 7) * 8;   // linear LDS dest (= lane*16 B)

#define STAGE_A(buf, u, kts) gload_lds16(gA + (size_t)(u) * 64 * Dq + (size_t)(kts) * 64, \
                                         &lds[(buf) * 32768 + (u) * 4096 + dstA])
#define STAGE_B(buf, u, kts) gload_lds16(gB + (size_t)(u) * 64 * Dq + (size_t)(kts) * 64, \
                                         &lds[(buf) * 32768 + 16384 + (u) * 4096 + dstA])
#define BARRIER() do { __builtin_amdgcn_sched_barrier(0); __builtin_amdgcn_s_barrier(); } while (0)

    f32x4 acc[8][4];
    #pragma unroll
    for (int i = 0; i < 8; ++i)
        #pragma unroll
        for (int j = 0; j < 4; ++j) acc[i][j] = {0.f, 0.f, 0.f, 0.f};

    // Prologue: K0 complete (8 units) + K1 partial (B0-3, A0, A2)
    STAGE_A(0, 0, 0); STAGE_A(0, 1, 0); STAGE_A(0, 2, 0); STAGE_A(0, 3, 0);
    STAGE_B(0, 0, 0); STAGE_B(0, 1, 0); STAGE_B(0, 2, 0); STAGE_B(0, 3, 0);
    STAGE_B(1, 0, 1); STAGE_B(1, 1, 1); STAGE_B(1, 2, 1); STAGE_B(1, 3, 1);
    STAGE_A(1, 0, 1); STAGE_A(1, 2, 1);
    asm volatile("s_waitcnt vmcnt(6)" ::: "memory");
    __builtin_amdgcn_s_barrier();

    const int arow = (wr + fr) * 64;
    const int brow = 16384 + (wc + fr) * 64;

#define LDA(q) do { \
    _Pragma("unroll") for (int m2 = 0; m2 < 2; ++m2) { \
        afr[m2][0] = *reinterpret_cast<const bf16x8*>(&lds[cbo + arow + ((q) * 32 + m2 * 16) * 64 + c0]); \
        afr[m2][1] = *reinterpret_cast<const bf16x8*>(&lds[cbo + arow + ((q) * 32 + m2 * 16) * 64 + c1]); } \
} while (0)
#define LDB() do { \
    _Pragma("unroll") for (int ni = 0; ni < 4; ++ni) { \
        bfr[ni][0] = *reinterpret_cast<const bf16x8*>(&lds[cbo + brow + ni * 1024 + c0]); \
        bfr[ni][1] = *reinterpret_cast<const bf16x8*>(&lds[cbo + brow + ni * 1024 + c1]); } \
} while (0)
// Operands swapped: A-operand = class frag (bfr), B-operand = emb frag (afr).
#define MFMA_QUAD(q) do { \
    __builtin_amdgcn_s_setprio(1); \
    _Pragma("unroll") for (int ks = 0; ks < 2; ++ks) \
    _Pragma("unroll") for (int m2 = 0; m2 < 2; ++m2) \
    _Pragma("unroll") for (int ni = 0; ni < 4; ++ni) \
        acc[2 * (q) + m2][ni] = __builtin_amdgcn_mfma_f32_16x16x32_bf16( \
            bfr[ni][ks], afr[m2][ks], acc[2 * (q) + m2][ni], 0, 0, 0); \
    __builtin_amdgcn_s_setprio(0); \
} while (0)

    #pragma unroll
    for (int kt = 0; kt < 8; ++kt) {
        const int cb = kt & 1, nb = cb ^ 1;
        const int cbo = cb * 32768;
        bf16x8 bfr[4][2];
        {
            bf16x8 afr[2][2];
            // ---- phase 0: ds B(all) + A quad0; stage A1,A3(kt+1)
            LDB(); LDA(0);
            if (kt < 7) { STAGE_A(nb, 1, kt + 1); STAGE_A(nb, 3, kt + 1); }
            BARRIER();
            MFMA_QUAD(0);
            BARRIER();
            // ---- phase 1: A quad1; stage B0,B1(kt+2)
            LDA(1);
            if (kt < 6) { STAGE_B(cb, 0, kt + 2); STAGE_B(cb, 1, kt + 2); }
            BARRIER();
            MFMA_QUAD(1);
            BARRIER();
            // ---- phase 2: A quad2; stage B2,B3(kt+2)
            LDA(2);
            if (kt < 6) { STAGE_B(cb, 2, kt + 2); STAGE_B(cb, 3, kt + 2); }
            BARRIER();
            MFMA_QUAD(2);
            BARRIER();
            // ---- phase 3: A quad3; stage A0,A2(kt+2); counted vmcnt gate
            LDA(3);
            if (kt < 6) { STAGE_A(cb, 0, kt + 2); STAGE_A(cb, 2, kt + 2); }
            BARRIER();
            MFMA_QUAD(3);
            if (kt < 6) asm volatile("s_waitcnt vmcnt(6)" ::: "memory");
            else        asm volatile("s_waitcnt vmcnt(0)" ::: "memory");
            BARRIER();
        }
    }

    // Epilogue (swapped-operand D mapping):
    //   emb row  = m0 + wr + mi*16 + fr
    //   class col = n0 + wc + ni*16 + kg*4 + reg   -> f32x4 is 4 consecutive cols
    const int ccol0 = wc + kg * 4;
    #pragma unroll
    for (int mi = 0; mi < 8; ++mi) {
        const int grow = m0 + wr + mi * 16 + fr;
        const int lab = labels[grow];
        float* orow = out + (size_t)grow * Cq + n0;
        #pragma unroll
        for (int ni = 0; ni < 4; ++ni) {
            const int col0 = ccol0 + ni * 16;
            const int gcol0 = n0 + col0;
            if (gcol0 >= Cq) continue;   // whole vector in padding (both %4==0)
            f32x4 v = acc[mi][ni];
            #pragma unroll
            for (int r = 0; r < 4; ++r) {
                if (gcol0 + r == lab) {
                    float c = v[r];
                    float sine = sqrtf(fmaxf(1.0f - c * c, 0.0f));
                    float phi = c * COS_M - sine * SIN_M;
                    v[r] = (c > THR) ? phi : (c - MM);
                }
            }
            v *= SCALE;
            *reinterpret_cast<f32x4*>(orow + col0) = v;   // 16B-aligned dwordx4
        }
    }
#undef STAGE_A
#undef STAGE_B
#undef BARRIER
#undef LDA
#undef LDB
#undef MFMA_QUAD
}

extern "C" void kernel_launch(void* const* d_in, const int* in_sizes, int n_in,
                              void* d_out, int out_size, void* d_ws, size_t ws_size,
                              hipStream_t stream)
{
    const float* emb    = (const float*)d_in[0];
    const int*   labels = (const int*)d_in[1];
    const float* weight = (const float*)d_in[2];
    float* out = (float*)d_out;

    unsigned short* Abf = (unsigned short*)d_ws;             // 2 MB
    unsigned short* Bbf = Abf + (size_t)Bq * Dq;             // 102.5 MB

    normalize_rows_kernel<<<Bq / 4, 256, 0, stream>>>(emb, Abf, Bq);
    normalize_rows_kernel<<<NPAD / 4, 256, 0, stream>>>(weight, Bbf, Cq);
    arc_gemm_kernel<<<8 * (NPAD / 256), 512, 131072, stream>>>(Abf, Bbf, labels, out);
}